// Round 8
// baseline (42.052 us; speedup 1.0000x reference)
//
#include <hip/hip_runtime.h>

typedef float f32x4 __attribute__((ext_vector_type(4)));

constexpr int B_ = 4;
constexpr int L_ = 4096;
constexpr int D_ = 128;
constexpr int K_ = 16;
constexpr int NKEY = 2 * K_;          // 32 candidates max
constexpr int GATHER_BLOCKS = 2048;   // 8 blocks/CU on 256 CUs
constexpr int GTHREADS = GATHER_BLOCKS * 256;           // 524288
constexpr int F4_TOTAL = B_ * L_ * K_ * (D_ / 4);       // 8,388,608 float4
constexpr int GATHER_ITERS = F4_TOTAL / GTHREADS;       // 16

static __device__ __forceinline__ int imin(int a, int b) { return a < b ? a : b; }
static __device__ __forceinline__ int imax(int a, int b) { return a > b ? a : b; }

// ---------------- kernel 1: exact top-K search, one query per thread -------
// (verbatim round-2/4, proven.) key = (dist<<12)|idx : ascending key ==
// ascending (dist, idx) == jax.lax.top_k order. Keys land in out_dist's
// storage; gather converts to float in place each call.
__global__ __launch_bounds__(64) void nbr_search_kernel(
    const int* __restrict__ fi, int* __restrict__ keyout)
{
    const int q = blockIdx.x * 64 + threadIdx.x;     // [0, B*L)
    const int b = q >> 12;
    const int i = q & (L_ - 1);
    const int* __restrict__ c = fi + b * L_;
    const int ci = c[i];

    // greedy two-pointer: 16-wide window holding the 16-smallest
    // distance multiset (contains ALL elements with dist < T)
    int lo = i, hi = i;
    #pragma unroll
    for (int t = 0; t < K_ - 1; ++t) {
        int dl = (lo > 0)      ? (ci - c[lo - 1]) : 0x7FFFFFFF;
        int dr = (hi < L_ - 1) ? (c[hi + 1] - ci) : 0x7FFFFFFF;
        if (dl <= dr) --lo; else ++hi;
    }
    const int T = imax(ci - c[lo], c[hi] - ci);

    int keys[NKEY];
    #pragma unroll
    for (int t = 0; t < K_; ++t) {
        int j = lo + t;
        int v = c[j];
        int d = (v < ci) ? (ci - v) : (v - ci);
        keys[t] = (d << 12) | j;
    }

    // left tie-run (value ci-T, indices < lo) can win the tie-break
    const int vL = ci - T;
    int j0 = -1;
    if (c[lo] == vL) j0 = lo;
    else if (lo > 0 && c[lo - 1] == vL) j0 = lo - 1;
    #pragma unroll
    for (int t = 0; t < K_; ++t) keys[K_ + t] = 0x7FFFFFFF;
    if (j0 >= 0) {
        int p = j0;
        while (p > 0 && c[p - 1] == vL) --p;         // run start (min index)
        const int e = imin(lo - 1, p + (K_ - 1));
        #pragma unroll
        for (int t = 0; t < K_; ++t) {
            int j = p + t;
            if (j <= e) keys[K_ + t] = (T << 12) | j;
        }
    }

    // bitonic sort, 32 keys, fully unrolled (registers only)
    #pragma unroll
    for (int size = 2; size <= NKEY; size <<= 1) {
        #pragma unroll
        for (int stride = size >> 1; stride > 0; stride >>= 1) {
            #pragma unroll
            for (int x = 0; x < NKEY; ++x) {
                int y = x ^ stride;
                if (y > x) {
                    bool up = ((x & size) == 0);
                    int a = keys[x], bb = keys[y];
                    int mn = imin(a, bb), mx = imax(a, bb);
                    keys[x] = up ? mn : mx;
                    keys[y] = up ? mx : mn;
                }
            }
        }
    }

    int4* ko = (int4*)(keyout + (size_t)q * K_);
    ko[0] = make_int4(keys[0],  keys[1],  keys[2],  keys[3]);
    ko[1] = make_int4(keys[4],  keys[5],  keys[6],  keys[7]);
    ko[2] = make_int4(keys[8],  keys[9],  keys[10], keys[11]);
    ko[3] = make_int4(keys[12], keys[13], keys[14], keys[15]);
}

// ---------------- kernel 2: GRID-STRIDED streaming gather ----------------
// A/B vs round 2: ONLY the store-address mapping changes. Iteration `it`
// writes the dense 8 MB band [it*GTHREADS, (it+1)*GTHREADS) float4s, thread
// gtid at offset gtid — the whole device sweeps one contiguous band together
// (fill-kernel pattern, maximal HBM row-buffer locality), instead of 2048
// private 64 KB streams at 2048 different row addresses.
// Hazard (round-2-proven): keys[row] is read only by the 32-lane group that
// owns f4 = row*32.. (broadcast), in the same wave and before the off==0
// lane's overwrite of out_dist[row] in program order.
__global__ __launch_bounds__(256) void nbr_gather_kernel(
    const float* __restrict__ attr, float* __restrict__ out_dist,
    float* __restrict__ out_attr)
{
    const int gtid = blockIdx.x * 256 + threadIdx.x;
    const int* __restrict__ keys = (const int*)out_dist;  // same storage

    #pragma unroll 4
    for (int it = 0; it < GATHER_ITERS; ++it) {
        int f4  = it * GTHREADS + gtid;    // < 2^23, fits int
        int row = f4 >> 5;                 // (q,k) row, 32 f4 per row
        int off = f4 & 31;
        int key = keys[row];               // broadcast across the 32 lanes
        int j   = key & (L_ - 1);
        int bb  = row >> 16;               // row / (L_*K_)
        const f32x4* __restrict__ src =
            (const f32x4*)attr + ((size_t)bb * L_ + j) * (D_ / 4);
        ((f32x4*)out_attr)[f4] = src[off];
        if (off == 0)                      // finalize distance in place
            out_dist[row] = (float)(key >> 12);
    }
}

extern "C" void kernel_launch(void* const* d_in, const int* in_sizes, int n_in,
                              void* d_out, int out_size, void* d_ws, size_t ws_size,
                              hipStream_t stream) {
    const int*   fi   = (const int*)d_in[0];     // [B, L, 1] int32 (sorted per b)
    const float* attr = (const float*)d_in[1];   // [B, L, D] float32
    float* out      = (float*)d_out;
    float* out_dist = out;                        // [B, L, K, 1]
    float* out_attr = out + (size_t)B_ * L_ * K_; // [B, L, K, D]

    nbr_search_kernel<<<dim3(B_ * L_ / 64), dim3(64), 0, stream>>>(
        fi, (int*)out_dist);
    nbr_gather_kernel<<<dim3(GATHER_BLOCKS), dim3(256), 0, stream>>>(
        attr, out_dist, out_attr);
}

// Round 9
// 32.932 us; speedup vs baseline: 1.2769x; 1.2769x over previous
//
#include <hip/hip_runtime.h>

typedef float f32x4 __attribute__((ext_vector_type(4)));

constexpr int B_ = 4;
constexpr int L_ = 4096;
constexpr int D_ = 128;
constexpr int K_ = 16;
constexpr int NKEY = 2 * K_;              // 32 candidates max
constexpr int QPB = 8;                    // queries per block
constexpr int BLOCKS = B_ * L_ / QPB;     // 2048 = 8 blocks/CU, one round
constexpr int PROWS = 38;                 // prefetched rows [i0-15, i0+22]
constexpr int PF4   = PROWS * (D_ / 4);   // 1216 float4

static __device__ __forceinline__ int imin(int a, int b) { return a < b ? a : b; }
static __device__ __forceinline__ int imax(int a, int b) { return a > b ? a : b; }

// Fused (R5 structure, best measured 32.2us) + two additions:
//  - waves 1..3 PREFETCH candidate attr rows into L2 concurrently with the
//    search (hides the ~2us serial-search bubble; warms gather reads).
//    No LDS, no gather-path changes (R7 showed LDS staging is neutral).
//  - gather store mapping: group g writes rows g*16..g*16+15 sequentially,
//    so each 32-lane group emits one strictly-ascending 512B-step stream.
__global__ __launch_bounds__(256, 8) void fused_nbr_kernel(
    const int* __restrict__ fi, const float* __restrict__ attr,
    float* __restrict__ out_dist, float* __restrict__ out_attr)
{
    __shared__ int s_nbr[QPB * K_];

    const int bid  = blockIdx.x;
    const int sbid = (bid & 7) * (BLOCKS / 8) + (bid >> 3);  // XCD-contiguous
    const int q0   = sbid * QPB;
    const int b    = q0 >> 12;
    const int i0   = q0 & (L_ - 1);
    const int* __restrict__ c = fi + b * L_;
    const f32x4* __restrict__ ab = (const f32x4*)(attr + (size_t)b * L_ * D_);
    const int tid = threadIdx.x;

    if (tid >= 64) {
        // ---- L2 prefetch of candidate rows (waves 1-3, coalesced) ----
        const int u0 = tid - 64;
        #pragma unroll
        for (int it = 0; it < 7; ++it) {
            int u = u0 + it * 192;
            if (u < PF4) {
                int r = u >> 5, off = u & 31;
                int g = imax(0, imin(L_ - 1, i0 - 15 + r));
                f32x4 v = ab[(size_t)g * 32 + off];
                asm volatile("" :: "v"(v[0]), "v"(v[3]));  // keep load live
            }
        }
    } else if (tid < QPB) {
        // ---- exact top-K search, one query per lane (PROVEN, verbatim) ----
        const int i  = i0 + tid;
        const int ci = c[i];

        // greedy two-pointer: 16-wide window holding the 16-smallest
        // distance multiset (contains ALL elements with dist < T)
        int lo = i, hi = i;
        #pragma unroll
        for (int t = 0; t < K_ - 1; ++t) {
            int dl = (lo > 0)      ? (ci - c[lo - 1]) : 0x7FFFFFFF;
            int dr = (hi < L_ - 1) ? (c[hi + 1] - ci) : 0x7FFFFFFF;
            if (dl <= dr) --lo; else ++hi;
        }
        const int T = imax(ci - c[lo], c[hi] - ci);

        // key = (dist<<12)|idx : ascending key == ascending (dist, idx),
        // exactly jax.lax.top_k tie-breaking (dist < 2^18, idx < 2^12).
        int keys[NKEY];
        #pragma unroll
        for (int t = 0; t < K_; ++t) {
            int j = lo + t;
            int v = c[j];
            int d = (v < ci) ? (ci - v) : (v - ci);
            keys[t] = (d << 12) | j;
        }

        // left tie-run (value ci-T, indices < lo) can win the tie-break
        const int vL = ci - T;
        int j0 = -1;
        if (c[lo] == vL) j0 = lo;
        else if (lo > 0 && c[lo - 1] == vL) j0 = lo - 1;
        #pragma unroll
        for (int t = 0; t < K_; ++t) keys[K_ + t] = 0x7FFFFFFF;
        if (j0 >= 0) {
            int p = j0;
            while (p > 0 && c[p - 1] == vL) --p;     // run start (min index)
            const int e = imin(lo - 1, p + (K_ - 1));
            #pragma unroll
            for (int t = 0; t < K_; ++t) {
                int j = p + t;
                if (j <= e) keys[K_ + t] = (T << 12) | j;
            }
        }

        // bitonic sort, 32 keys, fully unrolled (registers only)
        #pragma unroll
        for (int size = 2; size <= NKEY; size <<= 1) {
            #pragma unroll
            for (int stride = size >> 1; stride > 0; stride >>= 1) {
                #pragma unroll
                for (int x = 0; x < NKEY; ++x) {
                    int y = x ^ stride;
                    if (y > x) {
                        bool up = ((x & size) == 0);
                        int a = keys[x], bb = keys[y];
                        int mn = imin(a, bb), mx = imax(a, bb);
                        keys[x] = up ? mn : mx;
                        keys[y] = up ? mx : mn;
                    }
                }
            }
        }

        // emit: neighbor rows -> LDS, distances -> out_dist (exact float)
        float* od = out_dist + (size_t)(q0 + tid) * K_;
        #pragma unroll
        for (int t = 0; t < K_; ++t) {
            s_nbr[tid * K_ + t] = keys[t] & (L_ - 1);
            od[t] = (float)(keys[t] >> 12);
        }
    }
    __syncthreads();

    // ---- streaming gather: group g -> rows g*16..g*16+15, sequential ----
    f32x4* __restrict__ dst = (f32x4*)out_attr + (size_t)q0 * (K_ * D_ / 4);
    const int lane = tid & 31, grp = tid >> 5;
    #pragma unroll 8
    for (int it = 0; it < 16; ++it) {
        int row = grp * 16 + it;                // q_local*16 + k
        int j = s_nbr[row];                     // broadcast per 32-lane group
        dst[(size_t)row * 32 + lane] = ab[(size_t)j * 32 + lane];
    }
}

extern "C" void kernel_launch(void* const* d_in, const int* in_sizes, int n_in,
                              void* d_out, int out_size, void* d_ws, size_t ws_size,
                              hipStream_t stream) {
    const int*   fi   = (const int*)d_in[0];     // [B, L, 1] int32 (sorted per b)
    const float* attr = (const float*)d_in[1];   // [B, L, D] float32
    float* out      = (float*)d_out;
    float* out_dist = out;                        // [B, L, K, 1]
    float* out_attr = out + (size_t)B_ * L_ * K_; // [B, L, K, D]

    fused_nbr_kernel<<<dim3(BLOCKS), dim3(256), 0, stream>>>(
        fi, attr, out_dist, out_attr);
}

// Round 10
// 31.754 us; speedup vs baseline: 1.3243x; 1.0371x over previous
//
#include <hip/hip_runtime.h>

typedef float f32x4 __attribute__((ext_vector_type(4)));

constexpr int B_ = 4;
constexpr int L_ = 4096;
constexpr int D_ = 128;
constexpr int K_ = 16;
constexpr int NKEY = 2 * K_;              // 32 candidates max
constexpr int QPB = 32;                   // queries per block (dedup factor!)
constexpr int THREADS = 512;
constexpr int BLOCKS = B_ * L_ / QPB;     // 512 = 2 blocks/CU
constexpr int SROWS = QPB + 30;           // 62 staged rows [i0-15, i0+46]
constexpr int SF4   = SROWS * (D_ / 4);   // 1984 float4 = 31.7 KB

static __device__ __forceinline__ int imin(int a, int b) { return a < b ? a : b; }
static __device__ __forceinline__ int imax(int a, int b) { return a > b ? a : b; }

// QPB=32 to cut HBM read over-fetch: staging duplication = (QPB+30)/QPB =
// 1.94x (vs 4.75x at QPB=8). Staged fetch totals 16.3 MB vs ~33-40 MB for
// all previous variants. Search is the PROVEN greedy two-pointer (verbatim),
// 32 lanes of wave 0, one query per lane; waves 1-7 stage concurrently.
__global__ __launch_bounds__(512, 4) void fused_nbr_kernel(
    const int* __restrict__ fi, const float* __restrict__ attr,
    float* __restrict__ out_dist, float* __restrict__ out_attr)
{
    __shared__ f32x4 s_attr[SF4];
    __shared__ int   s_nbr[QPB * K_];

    const int bid  = blockIdx.x;
    const int sbid = (bid & 7) * (BLOCKS / 8) + (bid >> 3);  // XCD-contiguous
    const int q0   = sbid * QPB;
    const int b    = q0 >> 12;
    const int i0   = q0 & (L_ - 1);
    const int* __restrict__ c = fi + b * L_;
    const f32x4* __restrict__ ab = (const f32x4*)(attr + (size_t)b * L_ * D_);
    const int tid = threadIdx.x;

    if (tid >= 64) {
        // ---- stage rows [i0-15, i0+46] into LDS (waves 1-7, coalesced) ----
        const int u0 = tid - 64;
        #pragma unroll
        for (int it = 0; it < 5; ++it) {
            int u = u0 + it * (THREADS - 64);
            if (u < SF4) {
                int r = u >> 5, off = u & 31;
                int g = imax(0, imin(L_ - 1, i0 - 15 + r));
                s_attr[u] = ab[(size_t)g * 32 + off];
            }
        }
    } else if (tid < QPB) {
        // ---- exact top-K search, one query per lane (PROVEN, verbatim) ----
        const int i  = i0 + tid;
        const int ci = c[i];

        // greedy two-pointer: 16-wide window holding the 16-smallest
        // distance multiset (contains ALL elements with dist < T)
        int lo = i, hi = i;
        #pragma unroll
        for (int t = 0; t < K_ - 1; ++t) {
            int dl = (lo > 0)      ? (ci - c[lo - 1]) : 0x7FFFFFFF;
            int dr = (hi < L_ - 1) ? (c[hi + 1] - ci) : 0x7FFFFFFF;
            if (dl <= dr) --lo; else ++hi;
        }
        const int T = imax(ci - c[lo], c[hi] - ci);

        // key = (dist<<12)|idx : ascending key == ascending (dist, idx),
        // exactly jax.lax.top_k tie-breaking (dist < 2^18, idx < 2^12).
        int keys[NKEY];
        #pragma unroll
        for (int t = 0; t < K_; ++t) {
            int j = lo + t;
            int v = c[j];
            int d = (v < ci) ? (ci - v) : (v - ci);
            keys[t] = (d << 12) | j;
        }

        // left tie-run (value ci-T, indices < lo) can win the tie-break
        const int vL = ci - T;
        int j0 = -1;
        if (c[lo] == vL) j0 = lo;
        else if (lo > 0 && c[lo - 1] == vL) j0 = lo - 1;
        #pragma unroll
        for (int t = 0; t < K_; ++t) keys[K_ + t] = 0x7FFFFFFF;
        if (j0 >= 0) {
            int p = j0;
            while (p > 0 && c[p - 1] == vL) --p;     // run start (min index)
            const int e = imin(lo - 1, p + (K_ - 1));
            #pragma unroll
            for (int t = 0; t < K_; ++t) {
                int j = p + t;
                if (j <= e) keys[K_ + t] = (T << 12) | j;
            }
        }

        // bitonic sort, 32 keys, fully unrolled (registers only)
        #pragma unroll
        for (int size = 2; size <= NKEY; size <<= 1) {
            #pragma unroll
            for (int stride = size >> 1; stride > 0; stride >>= 1) {
                #pragma unroll
                for (int x = 0; x < NKEY; ++x) {
                    int y = x ^ stride;
                    if (y > x) {
                        bool up = ((x & size) == 0);
                        int a = keys[x], bb = keys[y];
                        int mn = imin(a, bb), mx = imax(a, bb);
                        keys[x] = up ? mn : mx;
                        keys[y] = up ? mx : mn;
                    }
                }
            }
        }

        // emit: neighbor rows -> LDS, distances -> out_dist (exact float)
        float* od = out_dist + (size_t)(q0 + tid) * K_;
        #pragma unroll
        for (int t = 0; t < K_; ++t) {
            s_nbr[tid * K_ + t] = keys[t] & (L_ - 1);
            od[t] = (float)(keys[t] >> 12);
        }
    }
    __syncthreads();

    // ---- streaming gather: 512 rows x 512 B from LDS, contiguous stores ----
    // Adjacent groups write adjacent rows each iteration -> each wave emits
    // 1 KB contiguous per iter (R5's proven mapping, scaled to 16 groups).
    f32x4* __restrict__ dst = (f32x4*)out_attr + (size_t)q0 * (K_ * D_ / 4);
    const int lane = tid & 31, grp = tid >> 5;   // grp in 0..15
    #pragma unroll 8
    for (int it = 0; it < 32; ++it) {
        int row = it * 16 + grp;                 // q_local*16 + k
        int j  = s_nbr[row];
        int lr = j - (i0 - 15);
        f32x4 val;
        if (__builtin_expect((unsigned)lr < (unsigned)SROWS, 1))
            val = s_attr[lr * 32 + lane];
        else                                     // rare: tie-run row far left
            val = ab[(size_t)j * 32 + lane];
        dst[(size_t)row * 32 + lane] = val;
    }
}

extern "C" void kernel_launch(void* const* d_in, const int* in_sizes, int n_in,
                              void* d_out, int out_size, void* d_ws, size_t ws_size,
                              hipStream_t stream) {
    const int*   fi   = (const int*)d_in[0];     // [B, L, 1] int32 (sorted per b)
    const float* attr = (const float*)d_in[1];   // [B, L, D] float32
    float* out      = (float*)d_out;
    float* out_dist = out;                        // [B, L, K, 1]
    float* out_attr = out + (size_t)B_ * L_ * K_; // [B, L, K, D]

    fused_nbr_kernel<<<dim3(BLOCKS), dim3(THREADS), 0, stream>>>(
        fi, attr, out_dist, out_attr);
}